// Round 3
// baseline (604.733 us; speedup 1.0000x reference)
//
#include <hip/hip_runtime.h>
#include <hip/hip_fp16.h>
#include <stdint.h>

// Linear4bit: out[t,n] = (sum_k a4[t,k]*w4[n,k]) * sx[t] * sw[n], fp16-rounded.
// KEY harness fact (round-3 fix): integer inputs arrive widened to int32 —
// one int32 per packed *byte*. A repack kernel compacts them to true packed
// bytes in d_ws; the GEMM (f16 MFMA, exact for int4 data) reads the compact
// form. Fallback template path stages directly from int32 if ws is tiny.

#define T_DIM 4096
#define K_DIM 4096
#define N_DIM 11008
#define KP    2048            // packed bytes per row
#define BM    128
#define BN    128
#define BK    64              // K elements per stage
#define BKP   32              // packed bytes per row per stage
#define STAGES 64
#define NA_BYTES ((size_t)T_DIM * KP)      // 8,388,608
#define NW_BYTES ((size_t)N_DIM * KP)      // 22,544,384

typedef __attribute__((ext_vector_type(4))) float    floatx4;
typedef __attribute__((ext_vector_type(8))) _Float16 f16x8;
typedef __attribute__((ext_vector_type(2))) _Float16 f16x2;

// ---- repack: int32 (one per packed byte, sign-extended) -> packed bytes ----
__global__ __launch_bounds__(256) void repack_int32_to_bytes(
    const int* __restrict__ xa, const int* __restrict__ xw,
    uint32_t* __restrict__ da, uint32_t* __restrict__ dw)
{
  const size_t i = (size_t)blockIdx.x * blockDim.x + threadIdx.x; // 1 per 4 elems
  const size_t na4 = NA_BYTES / 4;
  const int4* src; uint32_t* dst; size_t off;
  if (i < na4) { src = (const int4*)xa; dst = da; off = i; }
  else         { src = (const int4*)xw; dst = dw; off = i - na4; }
  const int4 v = src[off];
  dst[off] = (uint32_t)(v.x & 0xFF) | ((uint32_t)(v.y & 0xFF) << 8) |
             ((uint32_t)(v.z & 0xFF) << 16) | ((uint32_t)(v.w & 0xFF) << 24);
}

// two raw nibbles (bits[3:0], [19:16]) -> two exact signed f16 values
// bits(0x6408 ^ r) = f16(1032 + s), s = (r^8)-8; packed add of -1032 -> s.
__device__ __forceinline__ uint32_t cvt2(uint32_t m) {
  union U { uint32_t u; f16x2 h; } a, b, c;
  a.u = m ^ 0x64086408u;
  b.u = 0xE408E408u;
  c.h = a.h + b.h;            // v_pk_add_f16, exact
  return c.u;
}

// one packed dword (8 int4, k-chunk of 8) -> one 16B LDS cell of 8 f16.
// Within-cell k-permutation is identical for A and B (safe: symmetric k-maps).
__device__ __forceinline__ void unpack_cell(uint32_t* cell, uint32_t p) {
  cell[0] = cvt2( p        & 0x000F000Fu);
  cell[1] = cvt2((p >> 4)  & 0x000F000Fu);
  cell[2] = cvt2((p >> 8)  & 0x000F000Fu);
  cell[3] = cvt2((p >> 12) & 0x000F000Fu);
}

__device__ __forceinline__ uint32_t pack4(int4 v) {
  return (uint32_t)(v.x & 0xFF) | ((uint32_t)(v.y & 0xFF) << 8) |
         ((uint32_t)(v.z & 0xFF) << 16) | ((uint32_t)(v.w & 0xFF) << 24);
}

template <bool PACKED>
__global__ __launch_bounds__(256) void linear4bit_f16(
    const uint8_t* __restrict__ pqx, const float* __restrict__ sx,
    const uint8_t* __restrict__ wq,  const float* __restrict__ sw,
    const int* __restrict__ pqx32,   const int* __restrict__ wq32,
    float* __restrict__ out)
{
  // cell c (of 8) holds within-stage k [8c, 8c+8) for each row; 16B cells.
  __shared__ uint32_t sA[8][BM][4];   // 16 KB
  __shared__ uint32_t sB[8][BN][4];   // 16 KB

  const int tid  = threadIdx.x;
  const int lane = tid & 63;
  const int wv   = tid >> 6;          // 4 waves, 2x2 over the 128x128 tile
  const int wm   = wv >> 1, wn = wv & 1;
  const int q    = lane >> 4;         // quad (k-group of the 16x16x32 MFMA)
  const int m16  = lane & 15;         // m/n within 16-tile
  const int bm0  = blockIdx.x * BM;
  const int bn0  = blockIdx.y * BN;

  // staging: 2 threads per row, 16 packed bytes (32 int4) each per stage
  const int srow = tid >> 1, sh = tid & 1;
  const uint8_t* aPtr = pqx + (size_t)(bm0 + srow) * KP + sh * 16;
  const uint8_t* bPtr = wq  + (size_t)(bn0 + srow) * KP + sh * 16;
  const int* aPtr32 = pqx32 + (size_t)(bm0 + srow) * KP + sh * 16;
  const int* bPtr32 = wq32  + (size_t)(bn0 + srow) * KP + sh * 16;

  floatx4 acc[4][4];
#pragma unroll
  for (int mi = 0; mi < 4; ++mi)
#pragma unroll
    for (int ni = 0; ni < 4; ++ni)
#pragma unroll
      for (int r = 0; r < 4; ++r) acc[mi][ni][r] = 0.0f;

  uint4 ar, br;
  auto load_stage = [&](int s) {
    if (PACKED) {
      ar = *(const uint4*)(aPtr + (size_t)s * BKP);
      br = *(const uint4*)(bPtr + (size_t)s * BKP);
    } else {
      const int4* a4 = (const int4*)(aPtr32 + (size_t)s * BKP);
      const int4* b4 = (const int4*)(bPtr32 + (size_t)s * BKP);
      ar.x = pack4(a4[0]); ar.y = pack4(a4[1]);
      ar.z = pack4(a4[2]); ar.w = pack4(a4[3]);
      br.x = pack4(b4[0]); br.y = pack4(b4[1]);
      br.z = pack4(b4[2]); br.w = pack4(b4[3]);
    }
  };
  auto stage_to_lds = [&]() {
    uint32_t pa[4] = {ar.x, ar.y, ar.z, ar.w};
    uint32_t pb[4] = {br.x, br.y, br.z, br.w};
#pragma unroll
    for (int i = 0; i < 4; ++i) {
      unpack_cell(&sA[4 * sh + i][srow][0], pa[i]);
      unpack_cell(&sB[4 * sh + i][srow][0], pb[i]);
    }
  };

  load_stage(0);
  stage_to_lds();

#pragma unroll 1
  for (int s = 0; s < STAGES; ++s) {
    __syncthreads();                       // stage s visible in LDS
    if (s + 1 < STAGES) load_stage(s + 1); // register prefetch of stage s+1
#pragma unroll
    for (int s2 = 0; s2 < 2; ++s2) {       // two K=32 windows per stage
      f16x8 aF[4], bF[4];
#pragma unroll
      for (int mi = 0; mi < 4; ++mi)
        aF[mi] = *(const f16x8*)&sA[4 * s2 + q][wm * 64 + mi * 16 + m16][0];
#pragma unroll
      for (int ni = 0; ni < 4; ++ni)
        bF[ni] = *(const f16x8*)&sB[4 * s2 + q][wn * 64 + ni * 16 + m16][0];
#pragma unroll
      for (int mi = 0; mi < 4; ++mi)
#pragma unroll
        for (int ni = 0; ni < 4; ++ni)
          acc[mi][ni] = __builtin_amdgcn_mfma_f32_16x16x32_f16(
              aF[mi], bF[ni], acc[mi][ni], 0, 0, 0);
    }
    __syncthreads();                       // all reads of stage s done
    if (s + 1 < STAGES) stage_to_lds();    // overwrite LDS with stage s+1
  }

  // epilogue: 16x16 C/D layout (m89-verified): col = lane&15, row = quad*4+reg
#pragma unroll
  for (int mi = 0; mi < 4; ++mi) {
    const int grow0 = bm0 + wm * 64 + mi * 16 + q * 4;
    const float sx0 = sx[grow0 + 0], sx1 = sx[grow0 + 1];
    const float sx2 = sx[grow0 + 2], sx3 = sx[grow0 + 3];
#pragma unroll
    for (int ni = 0; ni < 4; ++ni) {
      const int gcol = bn0 + wn * 64 + ni * 16 + m16;
      const float swv = sw[gcol];
      const floatx4 a = acc[mi][ni];
      // reference rounding: (acc*sx)*sw in fp32, then fp16 round-trip
      out[(size_t)(grow0 + 0) * N_DIM + gcol] = __half2float(__float2half(a[0] * sx0 * swv));
      out[(size_t)(grow0 + 1) * N_DIM + gcol] = __half2float(__float2half(a[1] * sx1 * swv));
      out[(size_t)(grow0 + 2) * N_DIM + gcol] = __half2float(__float2half(a[2] * sx2 * swv));
      out[(size_t)(grow0 + 3) * N_DIM + gcol] = __half2float(__float2half(a[3] * sx3 * swv));
    }
  }
}

extern "C" void kernel_launch(void* const* d_in, const int* in_sizes, int n_in,
                              void* d_out, int out_size, void* d_ws, size_t ws_size,
                              hipStream_t stream) {
  const int*   pqx32 = (const int*)d_in[0];   // [4096*2048] int32, one per packed byte
  const float* sxp   = (const float*)d_in[1]; // [4096]
  const int*   wq32  = (const int*)d_in[2];   // [11008*2048] int32, one per packed byte
  const float* swp   = (const float*)d_in[3]; // [11008]
  float* outp = (float*)d_out;                // [4096, 11008] fp32 (fp16-rounded values)

  dim3 grid(T_DIM / BM, N_DIM / BN);          // (32, 86)

  if (ws_size >= NA_BYTES + NW_BYTES) {
    uint8_t* da = (uint8_t*)d_ws;
    uint8_t* dw = da + NA_BYTES;
    const size_t total4 = (NA_BYTES + NW_BYTES) / 4;     // 7,733,248 threads
    repack_int32_to_bytes<<<(uint32_t)(total4 / 256), 256, 0, stream>>>(
        pqx32, wq32, (uint32_t*)da, (uint32_t*)dw);
    linear4bit_f16<true><<<grid, dim3(256), 0, stream>>>(
        da, sxp, dw, swp, nullptr, nullptr, outp);
  } else {
    linear4bit_f16<false><<<grid, dim3(256), 0, stream>>>(
        nullptr, sxp, nullptr, swp, pqx32, wq32, outp);
  }
}

// Round 4
// 492.594 us; speedup vs baseline: 1.2276x; 1.2276x over previous
//
#include <hip/hip_runtime.h>
#include <hip/hip_fp16.h>
#include <stdint.h>

// Linear4bit: out[t,n] = (sum_k a4[t,k]*w4[n,k]) * sx[t] * sw[n], fp16-rounded.
// Inputs arrive int32-widened: one int32 per *packed byte* (two nibbles).
// Round-4: preprocess to int8 tile-images in d_ws, then i8 MFMA GEMM with
// pure global_load_lds staging (no VALU, no ds_write in the hot loop).
// Fallbacks: round-3 f16 paths if ws_size is too small (proven correct).

#define T_DIM 4096
#define K_DIM 4096
#define N_DIM 11008
#define KP    2048            // packed bytes (int32 elements) per row
#define BM 128
#define BN 128
#define BK 64
#define STAGES 64
#define A_PANELS (T_DIM / BM)   // 32
#define B_PANELS (N_DIM / BN)   // 86
#define CHUNK 8192              // one (panel,stage) tile image: 4 cells x 128 rows x 16B
#define WS_A ((size_t)A_PANELS * STAGES * CHUNK)   // 16,777,216
#define WS_B ((size_t)B_PANELS * STAGES * CHUNK)   // 45,088,768
#define NA_BYTES ((size_t)T_DIM * KP)              // fallback packed sizes
#define NW_BYTES ((size_t)N_DIM * KP)

typedef __attribute__((ext_vector_type(4)))  int int32x4;
typedef __attribute__((ext_vector_type(16))) int int32x16;
typedef __attribute__((ext_vector_type(4)))  float floatx4;
typedef __attribute__((ext_vector_type(8)))  _Float16 f16x8;
typedef __attribute__((ext_vector_type(2)))  _Float16 f16x2;

__device__ __forceinline__ uint32_t pack4(int4 v) {
  return (uint32_t)(v.x & 0xFF) | ((uint32_t)(v.y & 0xFF) << 8) |
         ((uint32_t)(v.z & 0xFF) << 16) | ((uint32_t)(v.w & 0xFF) << 24);
}
// borrow-free SWAR nibble -> signed int8 (per byte: ((x^8)|0x80)-8, then fix bit7)
__device__ __forceinline__ uint32_t nib_lo_s8(uint32_t p) {
  uint32_t t = (p & 0x0F0F0F0Fu) ^ 0x88888888u;
  return (t - 0x08080808u) ^ 0x80808080u;
}
__device__ __forceinline__ uint32_t nib_hi_s8(uint32_t p) {
  uint32_t t = ((p >> 4) & 0x0F0F0F0Fu) ^ 0x88888888u;
  return (t - 0x08080808u) ^ 0x80808080u;
}

// ---------------- preprocess: int32-widened -> int8 tile images ----------------
// One block per logical row. Thread g handles k [16g, 16g+16): stage s = g>>2,
// cell c = g&3. Cell byte order is a fixed k-permutation, identical for A and B
// (safe: MFMA A/B k-maps are symmetric). Reads: 2KB/wave contiguous.
__global__ __launch_bounds__(256) void unpack_tiles(
    const int* __restrict__ xa, const int* __restrict__ xw,
    uint8_t* __restrict__ wsa, uint8_t* __restrict__ wsb)
{
  const int row = blockIdx.x;
  const int g = threadIdx.x;
  const int s = g >> 2, c = g & 3;
  const int* src; uint8_t* dst; int r;
  if (row < T_DIM) {
    src = xa + (size_t)row * KP;
    r = row & (BM - 1);
    dst = wsa + ((size_t)((row >> 7) * STAGES + s)) * CHUNK;
  } else {
    const int rw = row - T_DIM;
    src = xw + (size_t)rw * KP;
    r = rw & (BN - 1);
    dst = wsb + ((size_t)((rw >> 7) * STAGES + s)) * CHUNK;
  }
  const int4* s4 = (const int4*)(src + g * 8);   // 8 int32 = packed bytes j..j+8
  const int4 v0 = s4[0], v1 = s4[1];
  const uint32_t b0 = pack4(v0), b1 = pack4(v1);
  uint4 o;                                        // 16 int8 covering k-window
  o.x = nib_lo_s8(b0); o.y = nib_hi_s8(b0);
  o.z = nib_lo_s8(b1); o.w = nib_hi_s8(b1);
  *(uint4*)(dst + c * 2048 + r * 16) = o;
}

// ---------------- i8 GEMM: DMA staging + v_mfma_i32_32x32x32_i8 ----------------
__device__ __forceinline__ void dma16(const uint8_t* g, uint8_t* l) {
  __builtin_amdgcn_global_load_lds(
      (const __attribute__((address_space(1))) uint32_t*)g,
      (__attribute__((address_space(3))) uint32_t*)l, 16, 0, 0);
}

__global__ __launch_bounds__(256) void gemm_i8(
    const uint8_t* __restrict__ wsa, const uint8_t* __restrict__ wsb,
    const float* __restrict__ sx, const float* __restrict__ sw,
    float* __restrict__ out)
{
  __shared__ uint8_t sA[CHUNK];   // [cell c][row][16B], cell = k-window [16c,16c+16)
  __shared__ uint8_t sB[CHUNK];

  const int tid  = threadIdx.x;
  const int lane = tid & 63;
  const int wv   = tid >> 6;           // 4 waves, 2x2 over 128x128
  const int wm   = wv >> 1, wn = wv & 1;
  const int h    = lane >> 5;          // k-half of the 32x32x32 MFMA
  const int ml   = lane & 31;
  const int p    = blockIdx.x;         // A panel
  const int q    = blockIdx.y;         // B panel

  const uint8_t* chunkA = wsa + (size_t)p * STAGES * CHUNK;
  const uint8_t* chunkB = wsb + (size_t)q * STAGES * CHUNK;
  // DMA: wave w fills segment [w*2048, w*2048+2048) of each tile (2 insts each)
  const int seg = wv * 2048 + lane * 16;
  uint8_t* ldsA0 = &sA[wv * 2048];
  uint8_t* ldsB0 = &sB[wv * 2048];

  const int rowA = (wm * 64 + ml) * 16;   // byte offset within a cell
  const int rowB = (wn * 64 + ml) * 16;

  int32x16 acc00, acc01, acc10, acc11;
#pragma unroll
  for (int i = 0; i < 16; ++i) { acc00[i] = 0; acc01[i] = 0; acc10[i] = 0; acc11[i] = 0; }

  // prologue: DMA stage 0
  dma16(chunkA + seg, ldsA0);
  dma16(chunkA + seg + 1024, ldsA0 + 1024);
  dma16(chunkB + seg, ldsB0);
  dma16(chunkB + seg + 1024, ldsB0 + 1024);

#pragma unroll 1
  for (int s = 0; s < STAGES; ++s) {
    __syncthreads();                   // drains vmcnt: stage s resident in LDS
#pragma unroll
    for (int s2 = 0; s2 < 2; ++s2) {   // two K=32 MFMA steps
      const uint8_t* pa = &sA[(2 * s2 + h) * 2048 + rowA];
      const uint8_t* pb = &sB[(2 * s2 + h) * 2048 + rowB];
      const int32x4 a0 = *(const int32x4*)pa;
      const int32x4 a1 = *(const int32x4*)(pa + 512);   // +32 rows
      const int32x4 b0 = *(const int32x4*)pb;
      const int32x4 b1 = *(const int32x4*)(pb + 512);
      acc00 = __builtin_amdgcn_mfma_i32_32x32x32_i8(a0, b0, acc00, 0, 0, 0);
      acc01 = __builtin_amdgcn_mfma_i32_32x32x32_i8(a0, b1, acc01, 0, 0, 0);
      acc10 = __builtin_amdgcn_mfma_i32_32x32x32_i8(a1, b0, acc10, 0, 0, 0);
      acc11 = __builtin_amdgcn_mfma_i32_32x32x32_i8(a1, b1, acc11, 0, 0, 0);
    }
    __syncthreads();                   // all reads of stage s done
    if (s + 1 < STAGES) {              // DMA stage s+1 over the same buffers
      const uint8_t* ca = chunkA + (size_t)(s + 1) * CHUNK + seg;
      const uint8_t* cb = chunkB + (size_t)(s + 1) * CHUNK + seg;
      dma16(ca, ldsA0);
      dma16(ca + 1024, ldsA0 + 1024);
      dma16(cb, ldsB0);
      dma16(cb + 1024, ldsB0 + 1024);
    }
  }

  // epilogue: C/D (verified): col = lane&31, row = (reg&3) + 8*(reg>>2) + 4*(lane>>5)
#pragma unroll
  for (int mi = 0; mi < 2; ++mi) {
    const int rb = p * BM + wm * 64 + mi * 32 + 4 * h;
#pragma unroll
    for (int ni = 0; ni < 2; ++ni) {
      const int gcol = q * BN + wn * 64 + ni * 32 + ml;
      const float swv = sw[gcol];
      const int32x16 a = (mi == 0) ? (ni == 0 ? acc00 : acc01)
                                   : (ni == 0 ? acc10 : acc11);
#pragma unroll
      for (int r = 0; r < 16; ++r) {
        const int grow = rb + (r & 3) + 8 * (r >> 2);
        const float v = (float)a[r] * sx[grow] * swv;   // reference mul order
        out[(size_t)grow * N_DIM + gcol] = __half2float(__float2half(v));
      }
    }
  }
}

// ================= fallback (round-3, proven): f16 MFMA paths =================
__global__ __launch_bounds__(256) void repack_int32_to_bytes(
    const int* __restrict__ xa, const int* __restrict__ xw,
    uint32_t* __restrict__ da, uint32_t* __restrict__ dw)
{
  const size_t i = (size_t)blockIdx.x * blockDim.x + threadIdx.x;
  const size_t na4 = NA_BYTES / 4;
  const int4* src; uint32_t* dst; size_t off;
  if (i < na4) { src = (const int4*)xa; dst = da; off = i; }
  else         { src = (const int4*)xw; dst = dw; off = i - na4; }
  const int4 v = src[off];
  dst[off] = pack4(v);
}

__device__ __forceinline__ uint32_t cvt2(uint32_t m) {
  union U { uint32_t u; f16x2 h; } a, b, c;
  a.u = m ^ 0x64086408u; b.u = 0xE408E408u; c.h = a.h + b.h;
  return c.u;
}
__device__ __forceinline__ void unpack_cell(uint32_t* cell, uint32_t p) {
  cell[0] = cvt2( p        & 0x000F000Fu);
  cell[1] = cvt2((p >> 4)  & 0x000F000Fu);
  cell[2] = cvt2((p >> 8)  & 0x000F000Fu);
  cell[3] = cvt2((p >> 12) & 0x000F000Fu);
}

template <bool PACKED>
__global__ __launch_bounds__(256) void linear4bit_f16(
    const uint8_t* __restrict__ pqx, const float* __restrict__ sx,
    const uint8_t* __restrict__ wq,  const float* __restrict__ sw,
    const int* __restrict__ pqx32,   const int* __restrict__ wq32,
    float* __restrict__ out)
{
  __shared__ uint32_t sAf[8][BM][4];
  __shared__ uint32_t sBf[8][BN][4];
  const int tid = threadIdx.x, lane = tid & 63, wv = tid >> 6;
  const int wm = wv >> 1, wn = wv & 1, qd = lane >> 4, m16 = lane & 15;
  const int bm0 = blockIdx.x * BM, bn0 = blockIdx.y * BN;
  const int srow = tid >> 1, sh = tid & 1;
  const uint8_t* aPtr = pqx + (size_t)(bm0 + srow) * KP + sh * 16;
  const uint8_t* bPtr = wq  + (size_t)(bn0 + srow) * KP + sh * 16;
  const int* aPtr32 = pqx32 + (size_t)(bm0 + srow) * KP + sh * 16;
  const int* bPtr32 = wq32  + (size_t)(bn0 + srow) * KP + sh * 16;
  floatx4 acc[4][4];
#pragma unroll
  for (int mi = 0; mi < 4; ++mi)
#pragma unroll
    for (int ni = 0; ni < 4; ++ni)
#pragma unroll
      for (int r = 0; r < 4; ++r) acc[mi][ni][r] = 0.0f;
  uint4 ar, br;
  auto load_stage = [&](int s) {
    if (PACKED) {
      ar = *(const uint4*)(aPtr + (size_t)s * 32);
      br = *(const uint4*)(bPtr + (size_t)s * 32);
    } else {
      const int4* a4 = (const int4*)(aPtr32 + (size_t)s * 32);
      const int4* b4 = (const int4*)(bPtr32 + (size_t)s * 32);
      ar.x = pack4(a4[0]); ar.y = pack4(a4[1]); ar.z = pack4(a4[2]); ar.w = pack4(a4[3]);
      br.x = pack4(b4[0]); br.y = pack4(b4[1]); br.z = pack4(b4[2]); br.w = pack4(b4[3]);
    }
  };
  auto stage_to_lds = [&]() {
    uint32_t pa[4] = {ar.x, ar.y, ar.z, ar.w};
    uint32_t pb[4] = {br.x, br.y, br.z, br.w};
#pragma unroll
    for (int i = 0; i < 4; ++i) {
      unpack_cell(&sAf[4 * sh + i][srow][0], pa[i]);
      unpack_cell(&sBf[4 * sh + i][srow][0], pb[i]);
    }
  };
  load_stage(0); stage_to_lds();
#pragma unroll 1
  for (int s = 0; s < STAGES; ++s) {
    __syncthreads();
    if (s + 1 < STAGES) load_stage(s + 1);
#pragma unroll
    for (int s2 = 0; s2 < 2; ++s2) {
      f16x8 aF[4], bF[4];
#pragma unroll
      for (int mi = 0; mi < 4; ++mi)
        aF[mi] = *(const f16x8*)&sAf[4 * s2 + qd][wm * 64 + mi * 16 + m16][0];
#pragma unroll
      for (int ni = 0; ni < 4; ++ni)
        bF[ni] = *(const f16x8*)&sBf[4 * s2 + qd][wn * 64 + ni * 16 + m16][0];
#pragma unroll
      for (int mi = 0; mi < 4; ++mi)
#pragma unroll
        for (int ni = 0; ni < 4; ++ni)
          acc[mi][ni] = __builtin_amdgcn_mfma_f32_16x16x32_f16(aF[mi], bF[ni], acc[mi][ni], 0, 0, 0);
    }
    __syncthreads();
    if (s + 1 < STAGES) stage_to_lds();
  }
#pragma unroll
  for (int mi = 0; mi < 4; ++mi) {
    const int grow0 = bm0 + wm * 64 + mi * 16 + qd * 4;
    const float s0 = sx[grow0], s1 = sx[grow0 + 1], s2v = sx[grow0 + 2], s3 = sx[grow0 + 3];
#pragma unroll
    for (int ni = 0; ni < 4; ++ni) {
      const int gcol = bn0 + wn * 64 + ni * 16 + m16;
      const float swv = sw[gcol];
      const floatx4 a = acc[mi][ni];
      out[(size_t)(grow0 + 0) * N_DIM + gcol] = __half2float(__float2half(a[0] * s0 * swv));
      out[(size_t)(grow0 + 1) * N_DIM + gcol] = __half2float(__float2half(a[1] * s1 * swv));
      out[(size_t)(grow0 + 2) * N_DIM + gcol] = __half2float(__float2half(a[2] * s2v * swv));
      out[(size_t)(grow0 + 3) * N_DIM + gcol] = __half2float(__float2half(a[3] * s3 * swv));
    }
  }
}

extern "C" void kernel_launch(void* const* d_in, const int* in_sizes, int n_in,
                              void* d_out, int out_size, void* d_ws, size_t ws_size,
                              hipStream_t stream) {
  const int*   pqx32 = (const int*)d_in[0];   // [4096*2048] int32 (one per packed byte)
  const float* sxp   = (const float*)d_in[1]; // [4096]
  const int*   wq32  = (const int*)d_in[2];   // [11008*2048] int32
  const float* swp   = (const float*)d_in[3]; // [11008]
  float* outp = (float*)d_out;                // [4096, 11008] fp32 (fp16-rounded)

  if (ws_size >= WS_A + WS_B) {
    uint8_t* wsa = (uint8_t*)d_ws;
    uint8_t* wsb = wsa + WS_A;
    unpack_tiles<<<T_DIM + N_DIM, 256, 0, stream>>>(pqx32, wq32, wsa, wsb);
    gemm_i8<<<dim3(A_PANELS, B_PANELS), 256, 0, stream>>>(wsa, wsb, sxp, swp, outp);
  } else if (ws_size >= NA_BYTES + NW_BYTES) {
    uint8_t* da = (uint8_t*)d_ws;
    uint8_t* dw = da + NA_BYTES;
    const size_t total4 = (NA_BYTES + NW_BYTES) / 4;
    repack_int32_to_bytes<<<(uint32_t)(total4 / 256), 256, 0, stream>>>(
        pqx32, wq32, (uint32_t*)da, (uint32_t*)dw);
    linear4bit_f16<true><<<dim3(T_DIM / BM, N_DIM / BN), 256, 0, stream>>>(
        da, sxp, dw, swp, nullptr, nullptr, outp);
  } else {
    linear4bit_f16<false><<<dim3(T_DIM / BM, N_DIM / BN), 256, 0, stream>>>(
        nullptr, sxp, nullptr, swp, pqx32, wq32, outp);
  }
}

// Round 5
// 477.721 us; speedup vs baseline: 1.2659x; 1.0311x over previous
//
#include <hip/hip_runtime.h>
#include <hip/hip_fp16.h>
#include <stdint.h>

// Linear4bit: out[t,n] = (sum_k a4[t,k]*w4[n,k]) * sx[t] * sw[n], fp16-rounded.
// Inputs arrive int32-widened: one int32 per *packed byte* (two nibbles).
// Round-5: (a) preprocess with coalesced writes -> int8 tile images in d_ws,
// (b) i8 MFMA GEMM, BM=128 x BN=256, double-buffered global_load_lds staging
// (DMA for stage s+1 issued before compute of stage s; 1 barrier/stage).

#define T_DIM 4096
#define K_DIM 4096
#define N_DIM 11008
#define KP    2048              // packed bytes (= int32 elements) per row
#define BM 128
#define BN 256
#define STAGES 64               // BK = 64
#define A_PANELS (T_DIM / BM)   // 32
#define B_PANELS (N_DIM / BN)   // 43
#define CHUNK_A 8192            // 4 cells x 128 rows x 16B
#define CHUNK_B 16384           // 4 cells x 256 rows x 16B
#define WS_A ((size_t)A_PANELS * STAGES * CHUNK_A)   // 16,777,216
#define WS_B ((size_t)B_PANELS * STAGES * CHUNK_B)   // 45,088,768
#define NA_BYTES ((size_t)T_DIM * KP)                // fallback packed sizes
#define NW_BYTES ((size_t)N_DIM * KP)

typedef __attribute__((ext_vector_type(4)))  int int32x4;
typedef __attribute__((ext_vector_type(16))) int int32x16;
typedef __attribute__((ext_vector_type(4)))  float floatx4;
typedef __attribute__((ext_vector_type(8)))  _Float16 f16x8;
typedef __attribute__((ext_vector_type(2)))  _Float16 f16x2;

__device__ __forceinline__ uint32_t pack4(int4 v) {
  return (uint32_t)(v.x & 0xFF) | ((uint32_t)(v.y & 0xFF) << 8) |
         ((uint32_t)(v.z & 0xFF) << 16) | ((uint32_t)(v.w & 0xFF) << 24);
}
// borrow-free SWAR nibble -> signed int8
__device__ __forceinline__ uint32_t nib_lo_s8(uint32_t p) {
  uint32_t t = (p & 0x0F0F0F0Fu) ^ 0x88888888u;
  return (t - 0x08080808u) ^ 0x80808080u;
}
__device__ __forceinline__ uint32_t nib_hi_s8(uint32_t p) {
  uint32_t t = ((p >> 4) & 0x0F0F0F0Fu) ^ 0x88888888u;
  return (t - 0x08080808u) ^ 0x80808080u;
}

// ---------------- preprocess: int32-widened -> int8 tile images ----------------
// grid (64 stages, 118 row-blocks): yb<32 -> A rows, else B rows (128 per block).
// Thread (r = t>>1, h = t&1) reads 16 int32 (64B contiguous) of row r covering
// k-halves of stage s; emits cells 2h, 2h+1 (16 int8 each). Per 16B store, a
// wave's lanes form two contiguous 512B runs (coalesced). Cell byte order is
// the same fixed k-permutation for A and B (safe: symmetric MFMA k-maps).
__global__ __launch_bounds__(256) void unpack_tiles2(
    const int* __restrict__ xa, const int* __restrict__ xw,
    uint8_t* __restrict__ wsa, uint8_t* __restrict__ wsb)
{
  const int s  = blockIdx.x;
  const int yb = blockIdx.y;
  const int t  = threadIdx.x;
  const int r  = t >> 1, h = t & 1;

  const int* src; uint8_t* dst; int cellStride;
  if (yb < A_PANELS) {
    src = xa + ((size_t)(yb * 128 + r)) * KP + s * 32 + h * 16;
    dst = wsa + ((size_t)yb * STAGES + s) * CHUNK_A + r * 16;
    cellStride = 2048;
  } else {
    const int yb2 = yb - A_PANELS;               // 0..85 (128-row blocks of B)
    const int panel = yb2 >> 1;
    const int rip = (yb2 & 1) * 128 + r;         // row within 256-row panel
    src = xw + ((size_t)(yb2 * 128 + r)) * KP + s * 32 + h * 16;
    dst = wsb + ((size_t)panel * STAGES + s) * CHUNK_B + rip * 16;
    cellStride = 4096;
  }
  const int4* s4 = (const int4*)src;             // 16 consecutive int32
  const int4 v0 = s4[0], v1 = s4[1], v2 = s4[2], v3 = s4[3];
  const uint32_t b0 = pack4(v0), b1 = pack4(v1);
  const uint32_t b2 = pack4(v2), b3 = pack4(v3);
  uint4 o01, o23;                                // two cells of 16 int8
  o01.x = nib_lo_s8(b0); o01.y = nib_hi_s8(b0);
  o01.z = nib_lo_s8(b1); o01.w = nib_hi_s8(b1);
  o23.x = nib_lo_s8(b2); o23.y = nib_hi_s8(b2);
  o23.z = nib_lo_s8(b3); o23.w = nib_hi_s8(b3);
  *(uint4*)(dst + (2 * h    ) * cellStride) = o01;
  *(uint4*)(dst + (2 * h + 1) * cellStride) = o23;
}

// ------- i8 GEMM: double-buffered DMA + v_mfma_i32_32x32x32_i8, 128x256 -------
__device__ __forceinline__ void dma16(const uint8_t* g, uint8_t* l) {
  __builtin_amdgcn_global_load_lds(
      (const __attribute__((address_space(1))) uint32_t*)g,
      (__attribute__((address_space(3))) uint32_t*)l, 16, 0, 0);
}

__global__ __launch_bounds__(256, 2) void gemm_i8_db(
    const uint8_t* __restrict__ wsa, const uint8_t* __restrict__ wsb,
    const float* __restrict__ sx, const float* __restrict__ sw,
    float* __restrict__ out)
{
  __shared__ uint8_t sA[2][CHUNK_A];   // [buf][cell c][row 128][16B]
  __shared__ uint8_t sB[2][CHUNK_B];   // [buf][cell c][row 256][16B]  (48 KB tot)

  const int tid  = threadIdx.x;
  const int lane = tid & 63;
  const int wv   = tid >> 6;           // 4 waves, 2(M) x 2(N)
  const int wm   = wv >> 1, wn = wv & 1;
  const int h    = lane >> 5;          // k-half of the 32x32x32 MFMA
  const int ml   = lane & 31;
  const int pp   = blockIdx.x;         // A panel (32)
  const int qq   = blockIdx.y;         // B panel (43)

  const uint8_t* chunkA = wsa + (size_t)pp * STAGES * CHUNK_A;
  const uint8_t* chunkB = wsb + (size_t)qq * STAGES * CHUNK_B;
  const int segOff = wv * 1024 + lane * 16;   // global per-lane
  const int ldsOff = wv * 1024;               // LDS base: wave-uniform (+lane*16 by HW)

  const int rowA = (wm * 64 + ml) * 16;       // byte offset inside a cell
  const int rowB = (wn * 128 + ml) * 16;

  int32x16 acc[2][4];
#pragma unroll
  for (int mi = 0; mi < 2; ++mi)
#pragma unroll
    for (int ni = 0; ni < 4; ++ni)
#pragma unroll
      for (int i = 0; i < 16; ++i) acc[mi][ni][i] = 0;

  auto dma_stage = [&](int s, int buf) {
    const uint8_t* ca = chunkA + (size_t)s * CHUNK_A;
    const uint8_t* cb = chunkB + (size_t)s * CHUNK_B;
#pragma unroll
    for (int i = 0; i < 2; ++i)        // A: 8 KB = 8 wave-chunks of 1 KB
      dma16(ca + segOff + i * 4096, &sA[buf][ldsOff + i * 4096]);
#pragma unroll
    for (int i = 0; i < 4; ++i)        // B: 16 KB = 16 wave-chunks of 1 KB
      dma16(cb + segOff + i * 4096, &sB[buf][ldsOff + i * 4096]);
  };

  dma_stage(0, 0);                     // prologue

#pragma unroll 1
  for (int s = 0; s < STAGES; ++s) {
    const int buf = s & 1;
    __syncthreads();                   // drains vmcnt: buf[s&1] resident; prior
                                       // reads of buf[1-s&1] (stage s-1) done
    if (s + 1 < STAGES) dma_stage(s + 1, buf ^ 1);   // overlapped with compute
#pragma unroll
    for (int s2 = 0; s2 < 2; ++s2) {   // two K=32 MFMA steps
      const int c = 2 * s2 + h;
      const uint8_t* pa = &sA[buf][c * 2048 + rowA];
      const uint8_t* pb = &sB[buf][c * 4096 + rowB];
      int32x4 aF[2], bF[4];
#pragma unroll
      for (int mi = 0; mi < 2; ++mi) aF[mi] = *(const int32x4*)(pa + mi * 512);
#pragma unroll
      for (int ni = 0; ni < 4; ++ni) bF[ni] = *(const int32x4*)(pb + ni * 512);
#pragma unroll
      for (int mi = 0; mi < 2; ++mi)
#pragma unroll
        for (int ni = 0; ni < 4; ++ni)
          acc[mi][ni] = __builtin_amdgcn_mfma_i32_32x32x32_i8(
              aF[mi], bF[ni], acc[mi][ni], 0, 0, 0);
    }
  }

  // epilogue: C/D (verified): col = lane&31, row = (reg&3) + 8*(reg>>2) + 4*(lane>>5)
#pragma unroll
  for (int mi = 0; mi < 2; ++mi) {
    const int rb = pp * BM + wm * 64 + mi * 32 + 4 * h;
    float sxv[16];
#pragma unroll
    for (int r = 0; r < 16; ++r) sxv[r] = sx[rb + (r & 3) + 8 * (r >> 2)];
#pragma unroll
    for (int ni = 0; ni < 4; ++ni) {
      const int gcol = qq * BN + wn * 128 + ni * 32 + ml;
      const float swv = sw[gcol];
#pragma unroll
      for (int r = 0; r < 16; ++r) {
        const int grow = rb + (r & 3) + 8 * (r >> 2);
        const float v = (float)acc[mi][ni][r] * sxv[r] * swv;  // ref mul order
        out[(size_t)grow * N_DIM + gcol] = __half2float(__float2half(v));
      }
    }
  }
}

// ================= fallback (round-3, proven): f16 MFMA paths =================
__global__ __launch_bounds__(256) void repack_int32_to_bytes(
    const int* __restrict__ xa, const int* __restrict__ xw,
    uint32_t* __restrict__ da, uint32_t* __restrict__ dw)
{
  const size_t i = (size_t)blockIdx.x * blockDim.x + threadIdx.x;
  const size_t na4 = NA_BYTES / 4;
  const int4* src; uint32_t* dst; size_t off;
  if (i < na4) { src = (const int4*)xa; dst = da; off = i; }
  else         { src = (const int4*)xw; dst = dw; off = i - na4; }
  const int4 v = src[off];
  dst[off] = pack4(v);
}

__device__ __forceinline__ uint32_t cvt2(uint32_t m) {
  union U { uint32_t u; f16x2 h; } a, b, c;
  a.u = m ^ 0x64086408u; b.u = 0xE408E408u; c.h = a.h + b.h;
  return c.u;
}
__device__ __forceinline__ void unpack_cell(uint32_t* cell, uint32_t p) {
  cell[0] = cvt2( p        & 0x000F000Fu);
  cell[1] = cvt2((p >> 4)  & 0x000F000Fu);
  cell[2] = cvt2((p >> 8)  & 0x000F000Fu);
  cell[3] = cvt2((p >> 12) & 0x000F000Fu);
}

template <bool PACKED>
__global__ __launch_bounds__(256) void linear4bit_f16(
    const uint8_t* __restrict__ pqx, const float* __restrict__ sx,
    const uint8_t* __restrict__ wq,  const float* __restrict__ sw,
    const int* __restrict__ pqx32,   const int* __restrict__ wq32,
    float* __restrict__ out)
{
  __shared__ uint32_t sAf[8][128][4];
  __shared__ uint32_t sBf[8][128][4];
  const int tid = threadIdx.x, lane = tid & 63, wv = tid >> 6;
  const int wm = wv >> 1, wn = wv & 1, qd = lane >> 4, m16 = lane & 15;
  const int bm0 = blockIdx.x * 128, bn0 = blockIdx.y * 128;
  const int srow = tid >> 1, sh = tid & 1;
  const uint8_t* aPtr = pqx + (size_t)(bm0 + srow) * KP + sh * 16;
  const uint8_t* bPtr = wq  + (size_t)(bn0 + srow) * KP + sh * 16;
  const int* aPtr32 = pqx32 + (size_t)(bm0 + srow) * KP + sh * 16;
  const int* bPtr32 = wq32  + (size_t)(bn0 + srow) * KP + sh * 16;
  floatx4 acc[4][4];
#pragma unroll
  for (int mi = 0; mi < 4; ++mi)
#pragma unroll
    for (int ni = 0; ni < 4; ++ni)
#pragma unroll
      for (int r = 0; r < 4; ++r) acc[mi][ni][r] = 0.0f;
  uint4 ar, br;
  auto load_stage = [&](int s) {
    if (PACKED) {
      ar = *(const uint4*)(aPtr + (size_t)s * 32);
      br = *(const uint4*)(bPtr + (size_t)s * 32);
    } else {
      const int4* a4 = (const int4*)(aPtr32 + (size_t)s * 32);
      const int4* b4 = (const int4*)(bPtr32 + (size_t)s * 32);
      ar.x = pack4(a4[0]); ar.y = pack4(a4[1]); ar.z = pack4(a4[2]); ar.w = pack4(a4[3]);
      br.x = pack4(b4[0]); br.y = pack4(b4[1]); br.z = pack4(b4[2]); br.w = pack4(b4[3]);
    }
  };
  auto stage_to_lds = [&]() {
    uint32_t pa[4] = {ar.x, ar.y, ar.z, ar.w};
    uint32_t pb[4] = {br.x, br.y, br.z, br.w};
#pragma unroll
    for (int i = 0; i < 4; ++i) {
      unpack_cell(&sAf[4 * sh + i][srow][0], pa[i]);
      unpack_cell(&sBf[4 * sh + i][srow][0], pb[i]);
    }
  };
  load_stage(0); stage_to_lds();
#pragma unroll 1
  for (int s = 0; s < STAGES; ++s) {
    __syncthreads();
    if (s + 1 < STAGES) load_stage(s + 1);
#pragma unroll
    for (int s2 = 0; s2 < 2; ++s2) {
      f16x8 aF[4], bF[4];
#pragma unroll
      for (int mi = 0; mi < 4; ++mi)
        aF[mi] = *(const f16x8*)&sAf[4 * s2 + qd][wm * 64 + mi * 16 + m16][0];
#pragma unroll
      for (int ni = 0; ni < 4; ++ni)
        bF[ni] = *(const f16x8*)&sBf[4 * s2 + qd][wn * 64 + ni * 16 + m16][0];
#pragma unroll
      for (int mi = 0; mi < 4; ++mi)
#pragma unroll
        for (int ni = 0; ni < 4; ++ni)
          acc[mi][ni] = __builtin_amdgcn_mfma_f32_16x16x32_f16(aF[mi], bF[ni], acc[mi][ni], 0, 0, 0);
    }
    __syncthreads();
    if (s + 1 < STAGES) stage_to_lds();
  }
#pragma unroll
  for (int mi = 0; mi < 4; ++mi) {
    const int grow0 = bm0 + wm * 64 + mi * 16 + qd * 4;
    const float s0 = sx[grow0], s1 = sx[grow0 + 1], s2v = sx[grow0 + 2], s3 = sx[grow0 + 3];
#pragma unroll
    for (int ni = 0; ni < 4; ++ni) {
      const int gcol = bn0 + wn * 64 + ni * 16 + m16;
      const float swv = sw[gcol];
      const floatx4 a = acc[mi][ni];
      out[(size_t)(grow0 + 0) * N_DIM + gcol] = __half2float(__float2half(a[0] * s0 * swv));
      out[(size_t)(grow0 + 1) * N_DIM + gcol] = __half2float(__float2half(a[1] * s1 * swv));
      out[(size_t)(grow0 + 2) * N_DIM + gcol] = __half2float(__float2half(a[2] * s2v * swv));
      out[(size_t)(grow0 + 3) * N_DIM + gcol] = __half2float(__float2half(a[3] * s3 * swv));
    }
  }
}

extern "C" void kernel_launch(void* const* d_in, const int* in_sizes, int n_in,
                              void* d_out, int out_size, void* d_ws, size_t ws_size,
                              hipStream_t stream) {
  const int*   pqx32 = (const int*)d_in[0];   // [4096*2048] int32 (one per packed byte)
  const float* sxp   = (const float*)d_in[1]; // [4096]
  const int*   wq32  = (const int*)d_in[2];   // [11008*2048] int32
  const float* swp   = (const float*)d_in[3]; // [11008]
  float* outp = (float*)d_out;                // [4096, 11008] fp32 (fp16-rounded)

  if (ws_size >= WS_A + WS_B) {
    uint8_t* wsa = (uint8_t*)d_ws;
    uint8_t* wsb = wsa + WS_A;
    unpack_tiles2<<<dim3(STAGES, A_PANELS + N_DIM / 128), 256, 0, stream>>>(
        pqx32, wq32, wsa, wsb);
    gemm_i8_db<<<dim3(A_PANELS, B_PANELS), 256, 0, stream>>>(wsa, wsb, sxp, swp, outp);
  } else if (ws_size >= NA_BYTES + NW_BYTES) {
    uint8_t* da = (uint8_t*)d_ws;
    uint8_t* dw = da + NA_BYTES;
    const size_t total4 = (NA_BYTES + NW_BYTES) / 4;
    repack_int32_to_bytes<<<(uint32_t)(total4 / 256), 256, 0, stream>>>(
        pqx32, wq32, (uint32_t*)da, (uint32_t*)dw);
    linear4bit_f16<true><<<dim3(T_DIM / 128, N_DIM / 128), 256, 0, stream>>>(
        da, sxp, dw, swp, nullptr, nullptr, outp);
  } else {
    linear4bit_f16<false><<<dim3(T_DIM / 128, N_DIM / 128), 256, 0, stream>>>(
        nullptr, sxp, nullptr, swp, pqx32, wq32, outp);
  }
}

// Round 6
// 477.106 us; speedup vs baseline: 1.2675x; 1.0013x over previous
//
#include <hip/hip_runtime.h>
#include <hip/hip_fp16.h>
#include <stdint.h>

// Linear4bit: out[t,n] = (sum_k a4[t,k]*w4[n,k]) * sx[t] * sw[n], fp16-rounded.
// Inputs arrive int32-widened: one int32 per *packed byte* (two nibbles).
// Round-6: i8 MFMA GEMM 128x256, TRIPLE-buffered global_load_lds staging with
// prefetch distance 2 and raw s_barrier + manual s_waitcnt vmcnt(6) — the
// barrier no longer drains the newest in-flight DMA (the round-5 940cyc/stage
// stall). Exactly 6 DMA insts/wave/stage -> vmcnt counting is exact.

#define T_DIM 4096
#define K_DIM 4096
#define N_DIM 11008
#define KP    2048              // packed bytes (= int32 elements) per row
#define BM 128
#define BN 256
#define STAGES 64               // BK = 64
#define A_PANELS (T_DIM / BM)   // 32
#define B_PANELS (N_DIM / BN)   // 43
#define CHUNK_A 8192            // 4 cells x 128 rows x 16B
#define CHUNK_B 16384           // 4 cells x 256 rows x 16B
#define WS_A ((size_t)A_PANELS * STAGES * CHUNK_A)   // 16,777,216
#define WS_B ((size_t)B_PANELS * STAGES * CHUNK_B)   // 45,088,768
#define NA_BYTES ((size_t)T_DIM * KP)                // fallback packed sizes
#define NW_BYTES ((size_t)N_DIM * KP)

typedef __attribute__((ext_vector_type(4)))  int int32x4;
typedef __attribute__((ext_vector_type(16))) int int32x16;
typedef __attribute__((ext_vector_type(4)))  float floatx4;
typedef __attribute__((ext_vector_type(8)))  _Float16 f16x8;
typedef __attribute__((ext_vector_type(2)))  _Float16 f16x2;

__device__ __forceinline__ uint32_t pack4(int4 v) {
  return (uint32_t)(v.x & 0xFF) | ((uint32_t)(v.y & 0xFF) << 8) |
         ((uint32_t)(v.z & 0xFF) << 16) | ((uint32_t)(v.w & 0xFF) << 24);
}
// borrow-free SWAR nibble -> signed int8
__device__ __forceinline__ uint32_t nib_lo_s8(uint32_t p) {
  uint32_t t = (p & 0x0F0F0F0Fu) ^ 0x88888888u;
  return (t - 0x08080808u) ^ 0x80808080u;
}
__device__ __forceinline__ uint32_t nib_hi_s8(uint32_t p) {
  uint32_t t = ((p >> 4) & 0x0F0F0F0Fu) ^ 0x88888888u;
  return (t - 0x08080808u) ^ 0x80808080u;
}

// ---------------- preprocess: int32-widened -> int8 tile images ----------------
// (unchanged from round 5 — coalesced 64B reads, 512B store runs)
__global__ __launch_bounds__(256) void unpack_tiles2(
    const int* __restrict__ xa, const int* __restrict__ xw,
    uint8_t* __restrict__ wsa, uint8_t* __restrict__ wsb)
{
  const int s  = blockIdx.x;
  const int yb = blockIdx.y;
  const int t  = threadIdx.x;
  const int r  = t >> 1, h = t & 1;

  const int* src; uint8_t* dst; int cellStride;
  if (yb < A_PANELS) {
    src = xa + ((size_t)(yb * 128 + r)) * KP + s * 32 + h * 16;
    dst = wsa + ((size_t)yb * STAGES + s) * CHUNK_A + r * 16;
    cellStride = 2048;
  } else {
    const int yb2 = yb - A_PANELS;               // 0..85 (128-row blocks of B)
    const int panel = yb2 >> 1;
    const int rip = (yb2 & 1) * 128 + r;         // row within 256-row panel
    src = xw + ((size_t)(yb2 * 128 + r)) * KP + s * 32 + h * 16;
    dst = wsb + ((size_t)panel * STAGES + s) * CHUNK_B + rip * 16;
    cellStride = 4096;
  }
  const int4* s4 = (const int4*)src;             // 16 consecutive int32
  const int4 v0 = s4[0], v1 = s4[1], v2 = s4[2], v3 = s4[3];
  const uint32_t b0 = pack4(v0), b1 = pack4(v1);
  const uint32_t b2 = pack4(v2), b3 = pack4(v3);
  uint4 o01, o23;                                // two cells of 16 int8
  o01.x = nib_lo_s8(b0); o01.y = nib_hi_s8(b0);
  o01.z = nib_lo_s8(b1); o01.w = nib_hi_s8(b1);
  o23.x = nib_lo_s8(b2); o23.y = nib_hi_s8(b2);
  o23.z = nib_lo_s8(b3); o23.w = nib_hi_s8(b3);
  *(uint4*)(dst + (2 * h    ) * cellStride) = o01;
  *(uint4*)(dst + (2 * h + 1) * cellStride) = o23;
}

// ------ i8 GEMM: 3-buffer DMA (distance 2) + raw barrier + manual vmcnt ------
__device__ __forceinline__ void dma16(const uint8_t* g, uint8_t* l) {
  __builtin_amdgcn_global_load_lds(
      (const __attribute__((address_space(1))) uint32_t*)g,
      (__attribute__((address_space(3))) uint32_t*)l, 16, 0, 0);
}

__global__ __launch_bounds__(256, 2) void gemm_i8_tb(
    const uint8_t* __restrict__ wsa, const uint8_t* __restrict__ wsb,
    const float* __restrict__ sx, const float* __restrict__ sw,
    float* __restrict__ out)
{
  __shared__ uint8_t sAmem[3 * CHUNK_A];   // 24 KB: 3 x [cell][row128][16B]
  __shared__ uint8_t sBmem[3 * CHUNK_B];   // 48 KB: 3 x [cell][row256][16B]

  const int tid  = threadIdx.x;
  const int lane = tid & 63;
  const int wv   = tid >> 6;           // 4 waves, 2(M) x 2(N)
  const int wm   = wv >> 1, wn = wv & 1;
  const int h    = lane >> 5;          // k-half of the 32x32x32 MFMA
  const int ml   = lane & 31;
  const int pp   = blockIdx.x;         // A panel (32)
  const int qq   = blockIdx.y;         // B panel (43)

  const uint8_t* chunkA = wsa + (size_t)pp * STAGES * CHUNK_A;
  const uint8_t* chunkB = wsb + (size_t)qq * STAGES * CHUNK_B;
  const int segOff = wv * 1024 + lane * 16;   // per-lane global offset
  const int ldsOff = wv * 1024;               // wave-uniform LDS base

  const int rowA = (wm * 64 + ml) * 16;       // byte offset inside a cell
  const int rowB = (wn * 128 + ml) * 16;

  int32x16 acc[2][4];
#pragma unroll
  for (int mi = 0; mi < 2; ++mi)
#pragma unroll
    for (int ni = 0; ni < 4; ++ni)
#pragma unroll
      for (int i = 0; i < 16; ++i) acc[mi][ni][i] = 0;

  // Exactly 6 global_load_lds per wave per call — vmcnt bookkeeping relies on it.
  auto dma_stage = [&](int s, int buf) {
    const uint8_t* ca = chunkA + (size_t)s * CHUNK_A;
    const uint8_t* cb = chunkB + (size_t)s * CHUNK_B;
    uint8_t* la = sAmem + buf * CHUNK_A + ldsOff;
    uint8_t* lb = sBmem + buf * CHUNK_B + ldsOff;
#pragma unroll
    for (int i = 0; i < 2; ++i)        // A: 8 KB = 8 wave-chunks of 1 KB
      dma16(ca + segOff + i * 4096, la + i * 4096);
#pragma unroll
    for (int i = 0; i < 4; ++i)        // B: 16 KB = 16 wave-chunks of 1 KB
      dma16(cb + segOff + i * 4096, lb + i * 4096);
  };

  dma_stage(0, 0);                     // prologue: stages 0,1 in flight (12)
  dma_stage(1, 1);

  int rb = 0;                          // read buffer  = s % 3
  int wb = 2;                          // write buffer = (s+2) % 3
#pragma unroll 1
  for (int s = 0; s < STAGES; ++s) {
    // Drain DMA(s) only; keep DMA(s+1) (6 newest) in flight across the barrier.
    if (s < STAGES - 1) asm volatile("s_waitcnt vmcnt(6)" ::: "memory");
    else                asm volatile("s_waitcnt vmcnt(0)" ::: "memory");
    __builtin_amdgcn_s_barrier();      // raw barrier: no compiler vmcnt(0) drain
    // Safe: buffer wb was last read at stage s-1; all waves passed the barrier
    // above, so those ds_reads (consumed by MFMAs before it) are complete.
    if (s + 2 < STAGES) dma_stage(s + 2, wb);

    const uint8_t* baseA = sAmem + rb * CHUNK_A;
    const uint8_t* baseB = sBmem + rb * CHUNK_B;
#pragma unroll
    for (int s2 = 0; s2 < 2; ++s2) {   // two K=32 MFMA steps
      const int c = 2 * s2 + h;
      const uint8_t* pa = baseA + c * 2048 + rowA;
      const uint8_t* pb = baseB + c * 4096 + rowB;
      int32x4 aF[2], bF[4];
#pragma unroll
      for (int mi = 0; mi < 2; ++mi) aF[mi] = *(const int32x4*)(pa + mi * 512);
#pragma unroll
      for (int ni = 0; ni < 4; ++ni) bF[ni] = *(const int32x4*)(pb + ni * 512);
#pragma unroll
      for (int mi = 0; mi < 2; ++mi)
#pragma unroll
        for (int ni = 0; ni < 4; ++ni)
          acc[mi][ni] = __builtin_amdgcn_mfma_i32_32x32x32_i8(
              aF[mi], bF[ni], acc[mi][ni], 0, 0, 0);
    }
    rb = (rb == 2) ? 0 : rb + 1;       // rotate buffers
    wb = (wb == 2) ? 0 : wb + 1;
  }

  // epilogue: C/D (verified): col = lane&31, row = (reg&3) + 8*(reg>>2) + 4*(lane>>5)
#pragma unroll
  for (int mi = 0; mi < 2; ++mi) {
    const int rbase = pp * BM + wm * 64 + mi * 32 + 4 * h;
    float sxv[16];
#pragma unroll
    for (int r = 0; r < 16; ++r) sxv[r] = sx[rbase + (r & 3) + 8 * (r >> 2)];
#pragma unroll
    for (int ni = 0; ni < 4; ++ni) {
      const int gcol = qq * BN + wn * 128 + ni * 32 + ml;
      const float swv = sw[gcol];
#pragma unroll
      for (int r = 0; r < 16; ++r) {
        const int grow = rbase + (r & 3) + 8 * (r >> 2);
        const float v = (float)acc[mi][ni][r] * sxv[r] * swv;  // ref mul order
        out[(size_t)grow * N_DIM + gcol] = __half2float(__float2half(v));
      }
    }
  }
}

// ================= fallback (round-3, proven): f16 MFMA paths =================
__global__ __launch_bounds__(256) void repack_int32_to_bytes(
    const int* __restrict__ xa, const int* __restrict__ xw,
    uint32_t* __restrict__ da, uint32_t* __restrict__ dw)
{
  const size_t i = (size_t)blockIdx.x * blockDim.x + threadIdx.x;
  const size_t na4 = NA_BYTES / 4;
  const int4* src; uint32_t* dst; size_t off;
  if (i < na4) { src = (const int4*)xa; dst = da; off = i; }
  else         { src = (const int4*)xw; dst = dw; off = i - na4; }
  const int4 v = src[off];
  dst[off] = pack4(v);
}

__device__ __forceinline__ uint32_t cvt2(uint32_t m) {
  union U { uint32_t u; f16x2 h; } a, b, c;
  a.u = m ^ 0x64086408u; b.u = 0xE408E408u; c.h = a.h + b.h;
  return c.u;
}
__device__ __forceinline__ void unpack_cell(uint32_t* cell, uint32_t p) {
  cell[0] = cvt2( p        & 0x000F000Fu);
  cell[1] = cvt2((p >> 4)  & 0x000F000Fu);
  cell[2] = cvt2((p >> 8)  & 0x000F000Fu);
  cell[3] = cvt2((p >> 12) & 0x000F000Fu);
}

template <bool PACKED>
__global__ __launch_bounds__(256) void linear4bit_f16(
    const uint8_t* __restrict__ pqx, const float* __restrict__ sx,
    const uint8_t* __restrict__ wq,  const float* __restrict__ sw,
    const int* __restrict__ pqx32,   const int* __restrict__ wq32,
    float* __restrict__ out)
{
  __shared__ uint32_t sAf[8][128][4];
  __shared__ uint32_t sBf[8][128][4];
  const int tid = threadIdx.x, lane = tid & 63, wv = tid >> 6;
  const int wm = wv >> 1, wn = wv & 1, qd = lane >> 4, m16 = lane & 15;
  const int bm0 = blockIdx.x * 128, bn0 = blockIdx.y * 128;
  const int srow = tid >> 1, sh = tid & 1;
  const uint8_t* aPtr = pqx + (size_t)(bm0 + srow) * KP + sh * 16;
  const uint8_t* bPtr = wq  + (size_t)(bn0 + srow) * KP + sh * 16;
  const int* aPtr32 = pqx32 + (size_t)(bm0 + srow) * KP + sh * 16;
  const int* bPtr32 = wq32  + (size_t)(bn0 + srow) * KP + sh * 16;
  floatx4 acc[4][4];
#pragma unroll
  for (int mi = 0; mi < 4; ++mi)
#pragma unroll
    for (int ni = 0; ni < 4; ++ni)
#pragma unroll
      for (int r = 0; r < 4; ++r) acc[mi][ni][r] = 0.0f;
  uint4 ar, br;
  auto load_stage = [&](int s) {
    if (PACKED) {
      ar = *(const uint4*)(aPtr + (size_t)s * 32);
      br = *(const uint4*)(bPtr + (size_t)s * 32);
    } else {
      const int4* a4 = (const int4*)(aPtr32 + (size_t)s * 32);
      const int4* b4 = (const int4*)(bPtr32 + (size_t)s * 32);
      ar.x = pack4(a4[0]); ar.y = pack4(a4[1]); ar.z = pack4(a4[2]); ar.w = pack4(a4[3]);
      br.x = pack4(b4[0]); br.y = pack4(b4[1]); br.z = pack4(b4[2]); br.w = pack4(b4[3]);
    }
  };
  auto stage_to_lds = [&]() {
    uint32_t pa[4] = {ar.x, ar.y, ar.z, ar.w};
    uint32_t pb[4] = {br.x, br.y, br.z, br.w};
#pragma unroll
    for (int i = 0; i < 4; ++i) {
      unpack_cell(&sAf[4 * sh + i][srow][0], pa[i]);
      unpack_cell(&sBf[4 * sh + i][srow][0], pb[i]);
    }
  };
  load_stage(0); stage_to_lds();
#pragma unroll 1
  for (int s = 0; s < STAGES; ++s) {
    __syncthreads();
    if (s + 1 < STAGES) load_stage(s + 1);
#pragma unroll
    for (int s2 = 0; s2 < 2; ++s2) {
      f16x8 aF[4], bF[4];
#pragma unroll
      for (int mi = 0; mi < 4; ++mi)
        aF[mi] = *(const f16x8*)&sAf[4 * s2 + qd][wm * 64 + mi * 16 + m16][0];
#pragma unroll
      for (int ni = 0; ni < 4; ++ni)
        bF[ni] = *(const f16x8*)&sBf[4 * s2 + qd][wn * 64 + ni * 16 + m16][0];
#pragma unroll
      for (int mi = 0; mi < 4; ++mi)
#pragma unroll
        for (int ni = 0; ni < 4; ++ni)
          acc[mi][ni] = __builtin_amdgcn_mfma_f32_16x16x32_f16(aF[mi], bF[ni], acc[mi][ni], 0, 0, 0);
    }
    __syncthreads();
    if (s + 1 < STAGES) stage_to_lds();
  }
#pragma unroll
  for (int mi = 0; mi < 4; ++mi) {
    const int grow0 = bm0 + wm * 64 + mi * 16 + qd * 4;
    const float s0 = sx[grow0], s1 = sx[grow0 + 1], s2v = sx[grow0 + 2], s3 = sx[grow0 + 3];
#pragma unroll
    for (int ni = 0; ni < 4; ++ni) {
      const int gcol = bn0 + wn * 64 + ni * 16 + m16;
      const float swv = sw[gcol];
      const floatx4 a = acc[mi][ni];
      out[(size_t)(grow0 + 0) * N_DIM + gcol] = __half2float(__float2half(a[0] * s0 * swv));
      out[(size_t)(grow0 + 1) * N_DIM + gcol] = __half2float(__float2half(a[1] * s1 * swv));
      out[(size_t)(grow0 + 2) * N_DIM + gcol] = __half2float(__float2half(a[2] * s2v * swv));
      out[(size_t)(grow0 + 3) * N_DIM + gcol] = __half2float(__float2half(a[3] * s3 * swv));
    }
  }
}

extern "C" void kernel_launch(void* const* d_in, const int* in_sizes, int n_in,
                              void* d_out, int out_size, void* d_ws, size_t ws_size,
                              hipStream_t stream) {
  const int*   pqx32 = (const int*)d_in[0];   // [4096*2048] int32 (one per packed byte)
  const float* sxp   = (const float*)d_in[1]; // [4096]
  const int*   wq32  = (const int*)d_in[2];   // [11008*2048] int32
  const float* swp   = (const float*)d_in[3]; // [11008]
  float* outp = (float*)d_out;                // [4096, 11008] fp32 (fp16-rounded)

  if (ws_size >= WS_A + WS_B) {
    uint8_t* wsa = (uint8_t*)d_ws;
    uint8_t* wsb = wsa + WS_A;
    unpack_tiles2<<<dim3(STAGES, A_PANELS + N_DIM / 128), 256, 0, stream>>>(
        pqx32, wq32, wsa, wsb);
    gemm_i8_tb<<<dim3(A_PANELS, B_PANELS), 256, 0, stream>>>(wsa, wsb, sxp, swp, outp);
  } else if (ws_size >= NA_BYTES + NW_BYTES) {
    uint8_t* da = (uint8_t*)d_ws;
    uint8_t* dw = da + NA_BYTES;
    const size_t total4 = (NA_BYTES + NW_BYTES) / 4;
    repack_int32_to_bytes<<<(uint32_t)(total4 / 256), 256, 0, stream>>>(
        pqx32, wq32, (uint32_t*)da, (uint32_t*)dw);
    linear4bit_f16<true><<<dim3(T_DIM / 128, N_DIM / 128), 256, 0, stream>>>(
        da, sxp, dw, swp, nullptr, nullptr, outp);
  } else {
    linear4bit_f16<false><<<dim3(T_DIM / 128, N_DIM / 128), 256, 0, stream>>>(
        nullptr, sxp, nullptr, swp, pqx32, wq32, outp);
  }
}